// Round 12
// baseline (445.368 us; speedup 1.0000x reference)
//
#include <hip/hip_runtime.h>
#include <math.h>

#define B 8
#define P 512
#define C 1024
#define H 8
#define BN_EPS 1e-5f

typedef __attribute__((ext_vector_type(8))) __bf16 bf16x8;
typedef __attribute__((ext_vector_type(4))) __bf16 bf16x4;
typedef __attribute__((ext_vector_type(4))) float f32x4;

// ---------------------------------------------------------------------------
// Kernel 0: split x (B,P,C) and W (C,C) into hi/lo bf16. One float4/thread.
// ---------------------------------------------------------------------------
__global__ __launch_bounds__(256) void split_hi_lo(
    const float* __restrict__ x, const float* __restrict__ Wq,
    __bf16* __restrict__ xhi, __bf16* __restrict__ xlo,
    __bf16* __restrict__ whi, __bf16* __restrict__ wlo)
{
    const size_t NX4 = (size_t)B * P * C / 4;
    size_t idx = (size_t)blockIdx.x * 256 + threadIdx.x;
    float4 v;
    __bf16 *dh, *dl;
    size_t o;
    if (idx < NX4) {
        v = ((const float4*)x)[idx];
        dh = xhi; dl = xlo; o = idx * 4;
    } else {
        v = ((const float4*)Wq)[idx - NX4];
        dh = whi; dl = wlo; o = (idx - NX4) * 4;
    }
    float f[4] = {v.x, v.y, v.z, v.w};
    bf16x4 hv, lv;
    #pragma unroll
    for (int j = 0; j < 4; ++j) {
        __bf16 hb = (__bf16)f[j];
        hv[j] = hb;
        lv[j] = (__bf16)(f[j] - (float)hb);
    }
    *(bf16x4*)&dh[o] = hv;
    *(bf16x4*)&dl[o] = lv;
}

// ---------------------------------------------------------------------------
// Kernel 1: Y[b,d,p] = BN( sum_c W[d,c] * x[b,p,c] ) via split-bf16 MFMA.
// (unchanged — proven)
// ---------------------------------------------------------------------------
__global__ __launch_bounds__(256) void qkv_bn_mfma(
    const __bf16* __restrict__ xhi, const __bf16* __restrict__ xlo,
    const __bf16* __restrict__ whi, const __bf16* __restrict__ wlo,
    const float* __restrict__ gamma, const float* __restrict__ beta,
    const float* __restrict__ mean, const float* __restrict__ var,
    __bf16* __restrict__ Yhi, __bf16* __restrict__ Ylo, __bf16* __restrict__ Zhi)
{
    const int dt = blockIdx.x;   // 16
    const int pt = blockIdx.y;   // 8
    const int b  = blockIdx.z;   // 8
    const int t = threadIdx.x, lane = t & 63, wid = t >> 6;
    const int quadd = (wid >> 1) * 32, quadp = (wid & 1) * 32;
    const int lr = lane & 15, lk = (lane >> 4) * 8;

    const int drow0 = dt * 64 + quadd + lr;
    const size_t xrow0 = ((size_t)b * P + pt * 64 + quadp + lr) * C;

    f32x4 acc[2][2];
    #pragma unroll
    for (int tm = 0; tm < 2; ++tm)
        #pragma unroll
        for (int tn = 0; tn < 2; ++tn)
            acc[tm][tn] = (f32x4){0.f, 0.f, 0.f, 0.f};

    for (int c0 = 0; c0 < C; c0 += 32) {
        const int col = c0 + lk;
        bf16x8 ah[2], al[2], bh[2], bl[2];
        #pragma unroll
        for (int tm = 0; tm < 2; ++tm) {
            size_t ia = (size_t)(drow0 + tm * 16) * C + col;
            ah[tm] = *(const bf16x8*)&whi[ia];
            al[tm] = *(const bf16x8*)&wlo[ia];
        }
        #pragma unroll
        for (int tn = 0; tn < 2; ++tn) {
            size_t ib = xrow0 + (size_t)tn * 16 * C + col;
            bh[tn] = *(const bf16x8*)&xhi[ib];
            bl[tn] = *(const bf16x8*)&xlo[ib];
        }
        #pragma unroll
        for (int tm = 0; tm < 2; ++tm)
            #pragma unroll
            for (int tn = 0; tn < 2; ++tn) {
                acc[tm][tn] = __builtin_amdgcn_mfma_f32_16x16x32_bf16(ah[tm], bh[tn], acc[tm][tn], 0, 0, 0);
                acc[tm][tn] = __builtin_amdgcn_mfma_f32_16x16x32_bf16(ah[tm], bl[tn], acc[tm][tn], 0, 0, 0);
                acc[tm][tn] = __builtin_amdgcn_mfma_f32_16x16x32_bf16(al[tm], bh[tn], acc[tm][tn], 0, 0, 0);
            }
    }

    const int rgrp = (lane >> 4) * 4;
    #pragma unroll
    for (int tm = 0; tm < 2; ++tm) {
        const int dbase = dt * 64 + quadd + tm * 16 + rgrp;
        float4 g4 = *(const float4*)&gamma[dbase];
        float4 bb4 = *(const float4*)&beta[dbase];
        float4 m4 = *(const float4*)&mean[dbase];
        float4 v4 = *(const float4*)&var[dbase];
        float gf[4] = {g4.x, g4.y, g4.z, g4.w};
        float bf[4] = {bb4.x, bb4.y, bb4.z, bb4.w};
        float mf[4] = {m4.x, m4.y, m4.z, m4.w};
        float vf[4] = {v4.x, v4.y, v4.z, v4.w};
        float sc[4];
        #pragma unroll
        for (int r = 0; r < 4; ++r) sc[r] = rsqrtf(vf[r] + BN_EPS) * gf[r];

        #pragma unroll
        for (int tn = 0; tn < 2; ++tn) {
            const int p = pt * 64 + quadp + tn * 16 + lr;
            bf16x4 zq;
            #pragma unroll
            for (int r = 0; r < 4; ++r) {
                float n = (acc[tm][tn][r] - mf[r]) * sc[r] + bf[r];
                __bf16 hb = (__bf16)n;
                __bf16 lb = (__bf16)(n - (float)hb);
                size_t yi = ((size_t)b * C + dbase + r) * P + p;
                Yhi[yi] = hb;
                Ylo[yi] = lb;
                zq[r] = hb;
            }
            *(bf16x4*)&Zhi[((size_t)b * P + p) * C + dbase] = zq;
        }
    }
}

// ---------------------------------------------------------------------------
// Kernel 2 (FUSED v8 = round-6 base + single-wave full-line attn stores
//                      + optional d-split for occupancy).
// Grid 512 or 1024: b = id&7 (XCD pin), ct = (id>>3)&63, dh = id>>9.
// Per it (nit windows of 64 d): wave w computes scores for d-slice w*16
// (all 8 heads), softmaxes in-register, writes P(bf16) to Plds ONLY.
// After the barrier:
//   phase 2a: wave w re-reads Plds for c-rows [w*4,w*4+4) x full 64 d x 8 h
//             and stores attn as f32x4 — 4x256B contiguous segments per
//             instruction, whole cache lines from ONE wave (no cross-wave
//             line assembly -> safe at high occupancy).
//   phase 2b: PV partial (unchanged).
// Epilogue: dh=0 -> out0, dh=1 -> ws partial (combined by add_partial).
// ---------------------------------------------------------------------------
__global__ __launch_bounds__(256, 4) void attn_fused(
    const __bf16* __restrict__ Yhi, const __bf16* __restrict__ Ylo,
    const __bf16* __restrict__ Zhi, const float* __restrict__ gs_ptr,
    float* __restrict__ attn, float* __restrict__ out0,
    float* __restrict__ part, int nit)
{
    const int id = blockIdx.x;
    const int b  = id & 7;            // XCD pin (dispatch round-robins XCDs)
    const int ct = (id >> 3) & 63;    // 0..63
    const int dhalf = id >> 9;        // 0 (grid 512) or 0/1 (grid 1024)
    const int c0 = ct * 16;
    const int t = threadIdx.x, lane = t & 63, w = t >> 6;
    const int lr = lane & 15;
    const int lg = lane >> 4;
    const int lk = lg * 8;
    const int rgrp = lg * 4;
    const float scale = 1.0f / gs_ptr[0];

    __shared__ __bf16 Plds[8][16][72];   // [h][c16][d64 pad] = 18 KB
    __shared__ float Olds[64][20];       // transpose buffer = 5 KB

    f32x4 out_acc[8];
    #pragma unroll
    for (int h = 0; h < H; ++h) out_acc[h] = (f32x4){0.f, 0.f, 0.f, 0.f};

    const size_t cbase = ((size_t)b * C + c0 + lr) * P;   // c-side row (A)

    for (int it = 0; it < nit; ++it) {
        const int dwin0 = dhalf * 512 + it * 64;           // block's d-window
        const int dwin  = dwin0 + w * 16;                  // wave's d-slice
        const size_t dbase = ((size_t)b * C + dwin + lr) * P;  // d-side row (B)

        // ---- phase 1: scores 16c x 16d (this wave's d-slice), all 8 heads
        f32x4 sacc[8];
        #pragma unroll
        for (int h = 0; h < H; ++h) sacc[h] = (f32x4){0.f, 0.f, 0.f, 0.f};

        #pragma unroll
        for (int h = 0; h < H; ++h) {
            #pragma unroll
            for (int s = 0; s < 2; ++s) {
                const int col = h * 64 + s * 32 + lk;
                bf16x8 ch_ = *(const bf16x8*)&Yhi[cbase + col];
                bf16x8 cl_ = *(const bf16x8*)&Ylo[cbase + col];
                bf16x8 bh_ = *(const bf16x8*)&Yhi[dbase + col];
                bf16x8 bl_ = *(const bf16x8*)&Ylo[dbase + col];
                sacc[h] = __builtin_amdgcn_mfma_f32_16x16x32_bf16(ch_, bh_, sacc[h], 0, 0, 0);
                sacc[h] = __builtin_amdgcn_mfma_f32_16x16x32_bf16(ch_, bl_, sacc[h], 0, 0, 0);
                sacc[h] = __builtin_amdgcn_mfma_f32_16x16x32_bf16(cl_, bh_, sacc[h], 0, 0, 0);
            }
        }

        // ---- softmax over h per (c,d); write P(bf16) to LDS only ----
        #pragma unroll
        for (int r = 0; r < 4; ++r) {
            float v[8];
            float m = -1e30f;
            #pragma unroll
            for (int h = 0; h < H; ++h) {
                v[h] = sacc[h][r] * scale;
                m = fmaxf(m, v[h]);
            }
            float ssum = 0.f;
            #pragma unroll
            for (int h = 0; h < H; ++h) { v[h] = __expf(v[h] - m); ssum += v[h]; }
            float inv = 1.0f / ssum;
            #pragma unroll
            for (int h = 0; h < H; ++h)
                Plds[h][rgrp + r][w * 16 + lr] = (__bf16)(v[h] * inv);
        }
        __syncthreads();

        // ---- phase 2a: attn stores — single-wave, full-line f32x4 ----
        {
            const int cr = w * 4 + (lane >> 4);       // this wave's 4 c-rows
            const int d4 = (lane & 15) * 4;           // 0..60
            #pragma unroll
            for (int h = 0; h < H; ++h) {
                bf16x4 pq = *(const bf16x4*)&Plds[h][cr][d4];
                f32x4 av;
                #pragma unroll
                for (int j = 0; j < 4; ++j) av[j] = (float)pq[j];
                *(f32x4*)&attn[(((size_t)(b * H + h) * C) + c0 + cr) * C + dwin0 + d4] = av;
            }
        }

        // ---- phase 2b: PV partial for this d-window (hi-only P, hi-only V) ----
        #pragma unroll
        for (int h = 0; h < H; ++h) {
            const int p = h * 64 + w * 16 + lr;
            #pragma unroll
            for (int kh = 0; kh < 2; ++kh) {
                bf16x8 bv = *(const bf16x8*)&Zhi[((size_t)b * P + p) * C + dwin0 + kh * 32 + lk];
                bf16x8 a = *(const bf16x8*)&Plds[h][lr][kh * 32 + lk];
                out_acc[h] = __builtin_amdgcn_mfma_f32_16x16x32_bf16(a, bv, out_acc[h], 0, 0, 0);
            }
        }
        __syncthreads();
    }

    // ---- epilogue: per head, LDS transpose then coalesced store ----
    float* dst = dhalf ? part : out0;
    #pragma unroll
    for (int h = 0; h < H; ++h) {
        #pragma unroll
        for (int r = 0; r < 4; ++r)
            Olds[w * 16 + lr][rgrp + r] = out_acc[h][r];
        __syncthreads();
        {
            const int row = t >> 2;            // 0..63 (p within head)
            const int coff = (t & 3) * 4;      // 0..12
            f32x4 vv = *(const f32x4*)&Olds[row][coff];
            *(f32x4*)&dst[((size_t)b * P + h * 64 + row) * C + c0 + coff] = vv;
        }
        __syncthreads();
    }
}

// ---------------------------------------------------------------------------
// Kernel 3: out0 += part (only in split mode).
// ---------------------------------------------------------------------------
__global__ __launch_bounds__(256) void add_partial(
    float* __restrict__ out0, const float* __restrict__ part)
{
    size_t i = ((size_t)blockIdx.x * 256 + threadIdx.x) * 4;
    f32x4 a = *(const f32x4*)&out0[i];
    f32x4 b = *(const f32x4*)&part[i];
    a += b;
    *(f32x4*)&out0[i] = a;
}

extern "C" void kernel_launch(void* const* d_in, const int* in_sizes, int n_in,
                              void* d_out, int out_size, void* d_ws, size_t ws_size,
                              hipStream_t stream) {
    const float* x     = (const float*)d_in[0];
    const float* Wq    = (const float*)d_in[1];
    const float* gamma = (const float*)d_in[2];
    const float* beta  = (const float*)d_in[3];
    const float* mean  = (const float*)d_in[4];
    const float* var   = (const float*)d_in[5];
    const float* gs    = (const float*)d_in[6];

    float* out0 = (float*)d_out;                          // h: (B,P,C)
    float* attn = (float*)d_out + (size_t)B * P * C;      // attn: (B,H,C,C)

    const size_t NE = (size_t)B * C * P;                  // 4M elements
    __bf16* Yhi = (__bf16*)d_ws;                          // 8 MB
    __bf16* Ylo = Yhi + NE;                               // 8 MB
    __bf16* Zhi = Ylo + NE;                               // 8 MB

    // out0-partial for the d-split: 16 MB at d_ws + 24 MB (if it fits)
    const size_t base = 3 * NE * sizeof(__bf16);          // 24 MB
    const bool split = ws_size >= base + NE * sizeof(float) * 4;  // +16 MB... (B*P*C f32)
    float* part = (float*)((char*)d_ws + base);

    // transient scratch in the attn-region tail (dead before attn is written)
    const size_t attn_elems = (size_t)B * H * C * C;
    __bf16* S = (__bf16*)(attn + (attn_elems - 5242880));
    __bf16* xhi = S;
    __bf16* xlo = xhi + (size_t)B * P * C;
    __bf16* whi = xlo + (size_t)B * P * C;
    __bf16* wlo = whi + (size_t)C * C;

    split_hi_lo<<<5120, 256, 0, stream>>>(x, Wq, xhi, xlo, whi, wlo);
    qkv_bn_mfma<<<dim3(16, 8, 8), 256, 0, stream>>>(xhi, xlo, whi, wlo,
                                                    gamma, beta, mean, var,
                                                    Yhi, Ylo, Zhi);
    if (split) {
        attn_fused<<<1024, 256, 0, stream>>>(Yhi, Ylo, Zhi, gs, attn, out0, part, 8);
        add_partial<<<4096, 256, 0, stream>>>(out0, part);
    } else {
        attn_fused<<<512, 256, 0, stream>>>(Yhi, Ylo, Zhi, gs, attn, out0, part, 16);
    }
}

// Round 13
// 424.229 us; speedup vs baseline: 1.0498x; 1.0498x over previous
//
#include <hip/hip_runtime.h>
#include <math.h>

#define B 8
#define P 512
#define C 1024
#define H 8
#define BN_EPS 1e-5f

typedef __attribute__((ext_vector_type(8))) __bf16 bf16x8;
typedef __attribute__((ext_vector_type(4))) __bf16 bf16x4;
typedef __attribute__((ext_vector_type(4))) float f32x4;

// ---------------------------------------------------------------------------
// Kernel 0: split x (B,P,C) and W (C,C) into hi/lo bf16. One float4/thread.
// ---------------------------------------------------------------------------
__global__ __launch_bounds__(256) void split_hi_lo(
    const float* __restrict__ x, const float* __restrict__ Wq,
    __bf16* __restrict__ xhi, __bf16* __restrict__ xlo,
    __bf16* __restrict__ whi, __bf16* __restrict__ wlo)
{
    const size_t NX4 = (size_t)B * P * C / 4;
    size_t idx = (size_t)blockIdx.x * 256 + threadIdx.x;
    float4 v;
    __bf16 *dh, *dl;
    size_t o;
    if (idx < NX4) {
        v = ((const float4*)x)[idx];
        dh = xhi; dl = xlo; o = idx * 4;
    } else {
        v = ((const float4*)Wq)[idx - NX4];
        dh = whi; dl = wlo; o = (idx - NX4) * 4;
    }
    float f[4] = {v.x, v.y, v.z, v.w};
    bf16x4 hv, lv;
    #pragma unroll
    for (int j = 0; j < 4; ++j) {
        __bf16 hb = (__bf16)f[j];
        hv[j] = hb;
        lv[j] = (__bf16)(f[j] - (float)hb);
    }
    *(bf16x4*)&dh[o] = hv;
    *(bf16x4*)&dl[o] = lv;
}

// ---------------------------------------------------------------------------
// Kernel 1: Y[b,d,p] = BN( sum_c W[d,c] * x[b,p,c] ) via split-bf16 MFMA.
// (unchanged — proven)
// ---------------------------------------------------------------------------
__global__ __launch_bounds__(256) void qkv_bn_mfma(
    const __bf16* __restrict__ xhi, const __bf16* __restrict__ xlo,
    const __bf16* __restrict__ whi, const __bf16* __restrict__ wlo,
    const float* __restrict__ gamma, const float* __restrict__ beta,
    const float* __restrict__ mean, const float* __restrict__ var,
    __bf16* __restrict__ Yhi, __bf16* __restrict__ Ylo, __bf16* __restrict__ Zhi)
{
    const int dt = blockIdx.x;   // 16
    const int pt = blockIdx.y;   // 8
    const int b  = blockIdx.z;   // 8
    const int t = threadIdx.x, lane = t & 63, wid = t >> 6;
    const int quadd = (wid >> 1) * 32, quadp = (wid & 1) * 32;
    const int lr = lane & 15, lk = (lane >> 4) * 8;

    const int drow0 = dt * 64 + quadd + lr;
    const size_t xrow0 = ((size_t)b * P + pt * 64 + quadp + lr) * C;

    f32x4 acc[2][2];
    #pragma unroll
    for (int tm = 0; tm < 2; ++tm)
        #pragma unroll
        for (int tn = 0; tn < 2; ++tn)
            acc[tm][tn] = (f32x4){0.f, 0.f, 0.f, 0.f};

    for (int c0 = 0; c0 < C; c0 += 32) {
        const int col = c0 + lk;
        bf16x8 ah[2], al[2], bh[2], bl[2];
        #pragma unroll
        for (int tm = 0; tm < 2; ++tm) {
            size_t ia = (size_t)(drow0 + tm * 16) * C + col;
            ah[tm] = *(const bf16x8*)&whi[ia];
            al[tm] = *(const bf16x8*)&wlo[ia];
        }
        #pragma unroll
        for (int tn = 0; tn < 2; ++tn) {
            size_t ib = xrow0 + (size_t)tn * 16 * C + col;
            bh[tn] = *(const bf16x8*)&xhi[ib];
            bl[tn] = *(const bf16x8*)&xlo[ib];
        }
        #pragma unroll
        for (int tm = 0; tm < 2; ++tm)
            #pragma unroll
            for (int tn = 0; tn < 2; ++tn) {
                acc[tm][tn] = __builtin_amdgcn_mfma_f32_16x16x32_bf16(ah[tm], bh[tn], acc[tm][tn], 0, 0, 0);
                acc[tm][tn] = __builtin_amdgcn_mfma_f32_16x16x32_bf16(ah[tm], bl[tn], acc[tm][tn], 0, 0, 0);
                acc[tm][tn] = __builtin_amdgcn_mfma_f32_16x16x32_bf16(al[tm], bh[tn], acc[tm][tn], 0, 0, 0);
            }
    }

    const int rgrp = (lane >> 4) * 4;
    #pragma unroll
    for (int tm = 0; tm < 2; ++tm) {
        const int dbase = dt * 64 + quadd + tm * 16 + rgrp;
        float4 g4 = *(const float4*)&gamma[dbase];
        float4 bb4 = *(const float4*)&beta[dbase];
        float4 m4 = *(const float4*)&mean[dbase];
        float4 v4 = *(const float4*)&var[dbase];
        float gf[4] = {g4.x, g4.y, g4.z, g4.w};
        float bf[4] = {bb4.x, bb4.y, bb4.z, bb4.w};
        float mf[4] = {m4.x, m4.y, m4.z, m4.w};
        float vf[4] = {v4.x, v4.y, v4.z, v4.w};
        float sc[4];
        #pragma unroll
        for (int r = 0; r < 4; ++r) sc[r] = rsqrtf(vf[r] + BN_EPS) * gf[r];

        #pragma unroll
        for (int tn = 0; tn < 2; ++tn) {
            const int p = pt * 64 + quadp + tn * 16 + lr;
            bf16x4 zq;
            #pragma unroll
            for (int r = 0; r < 4; ++r) {
                float n = (acc[tm][tn][r] - mf[r]) * sc[r] + bf[r];
                __bf16 hb = (__bf16)n;
                __bf16 lb = (__bf16)(n - (float)hb);
                size_t yi = ((size_t)b * C + dbase + r) * P + p;
                Yhi[yi] = hb;
                Ylo[yi] = lb;
                zq[r] = hb;
            }
            *(bf16x4*)&Zhi[((size_t)b * P + p) * C + dbase] = zq;
        }
    }
}

// ---------------------------------------------------------------------------
// Kernel 2 (FUSED v9 = round-12 structure + NON-TEMPORAL attn stores).
// The attn write stream previously drained through the XCD L2 as dirty
// lines; at 4 blocks/CU the in-flight dirty data (~128 blk x 32 KB = 4 MB)
// owned the whole L2 and evicted the 3 MB Y working set -> 397 MB re-fetch
// (round-12 counters). nt stores keep the streaming writes from displacing
// Y, making high occupancy compatible with L2 residency.
// ---------------------------------------------------------------------------
__global__ __launch_bounds__(256, 4) void attn_fused(
    const __bf16* __restrict__ Yhi, const __bf16* __restrict__ Ylo,
    const __bf16* __restrict__ Zhi, const float* __restrict__ gs_ptr,
    float* __restrict__ attn, float* __restrict__ out0,
    float* __restrict__ part, int nit)
{
    const int id = blockIdx.x;
    const int b  = id & 7;            // XCD pin (dispatch round-robins XCDs)
    const int ct = (id >> 3) & 63;    // 0..63
    const int dhalf = id >> 9;        // 0 (grid 512) or 0/1 (grid 1024)
    const int c0 = ct * 16;
    const int t = threadIdx.x, lane = t & 63, w = t >> 6;
    const int lr = lane & 15;
    const int lg = lane >> 4;
    const int lk = lg * 8;
    const int rgrp = lg * 4;
    const float scale = 1.0f / gs_ptr[0];

    __shared__ __bf16 Plds[8][16][72];   // [h][c16][d64 pad] = 18 KB
    __shared__ float Olds[64][20];       // transpose buffer = 5 KB

    f32x4 out_acc[8];
    #pragma unroll
    for (int h = 0; h < H; ++h) out_acc[h] = (f32x4){0.f, 0.f, 0.f, 0.f};

    const size_t cbase = ((size_t)b * C + c0 + lr) * P;   // c-side row (A)

    for (int it = 0; it < nit; ++it) {
        const int dwin0 = dhalf * 512 + it * 64;           // block's d-window
        const int dwin  = dwin0 + w * 16;                  // wave's d-slice
        const size_t dbase = ((size_t)b * C + dwin + lr) * P;  // d-side row (B)

        // ---- phase 1: scores 16c x 16d (this wave's d-slice), all 8 heads
        f32x4 sacc[8];
        #pragma unroll
        for (int h = 0; h < H; ++h) sacc[h] = (f32x4){0.f, 0.f, 0.f, 0.f};

        #pragma unroll
        for (int h = 0; h < H; ++h) {
            #pragma unroll
            for (int s = 0; s < 2; ++s) {
                const int col = h * 64 + s * 32 + lk;
                bf16x8 ch_ = *(const bf16x8*)&Yhi[cbase + col];
                bf16x8 cl_ = *(const bf16x8*)&Ylo[cbase + col];
                bf16x8 bh_ = *(const bf16x8*)&Yhi[dbase + col];
                bf16x8 bl_ = *(const bf16x8*)&Ylo[dbase + col];
                sacc[h] = __builtin_amdgcn_mfma_f32_16x16x32_bf16(ch_, bh_, sacc[h], 0, 0, 0);
                sacc[h] = __builtin_amdgcn_mfma_f32_16x16x32_bf16(ch_, bl_, sacc[h], 0, 0, 0);
                sacc[h] = __builtin_amdgcn_mfma_f32_16x16x32_bf16(cl_, bh_, sacc[h], 0, 0, 0);
            }
        }

        // ---- softmax over h per (c,d); write P(bf16) to LDS only ----
        #pragma unroll
        for (int r = 0; r < 4; ++r) {
            float v[8];
            float m = -1e30f;
            #pragma unroll
            for (int h = 0; h < H; ++h) {
                v[h] = sacc[h][r] * scale;
                m = fmaxf(m, v[h]);
            }
            float ssum = 0.f;
            #pragma unroll
            for (int h = 0; h < H; ++h) { v[h] = __expf(v[h] - m); ssum += v[h]; }
            float inv = 1.0f / ssum;
            #pragma unroll
            for (int h = 0; h < H; ++h)
                Plds[h][rgrp + r][w * 16 + lr] = (__bf16)(v[h] * inv);
        }
        __syncthreads();

        // ---- phase 2a: attn stores — single-wave full lines, NON-TEMPORAL ----
        {
            const int cr = w * 4 + (lane >> 4);       // this wave's 4 c-rows
            const int d4 = (lane & 15) * 4;           // 0..60
            #pragma unroll
            for (int h = 0; h < H; ++h) {
                bf16x4 pq = *(const bf16x4*)&Plds[h][cr][d4];
                f32x4 av;
                #pragma unroll
                for (int j = 0; j < 4; ++j) av[j] = (float)pq[j];
                __builtin_nontemporal_store(av,
                    (f32x4*)&attn[(((size_t)(b * H + h) * C) + c0 + cr) * C + dwin0 + d4]);
            }
        }

        // ---- phase 2b: PV partial for this d-window (hi-only P, hi-only V) ----
        #pragma unroll
        for (int h = 0; h < H; ++h) {
            const int p = h * 64 + w * 16 + lr;
            #pragma unroll
            for (int kh = 0; kh < 2; ++kh) {
                bf16x8 bv = *(const bf16x8*)&Zhi[((size_t)b * P + p) * C + dwin0 + kh * 32 + lk];
                bf16x8 a = *(const bf16x8*)&Plds[h][lr][kh * 32 + lk];
                out_acc[h] = __builtin_amdgcn_mfma_f32_16x16x32_bf16(a, bv, out_acc[h], 0, 0, 0);
            }
        }
        __syncthreads();
    }

    // ---- epilogue: per head, LDS transpose then coalesced nt store ----
    float* dst = dhalf ? part : out0;
    #pragma unroll
    for (int h = 0; h < H; ++h) {
        #pragma unroll
        for (int r = 0; r < 4; ++r)
            Olds[w * 16 + lr][rgrp + r] = out_acc[h][r];
        __syncthreads();
        {
            const int row = t >> 2;            // 0..63 (p within head)
            const int coff = (t & 3) * 4;      // 0..12
            f32x4 vv = *(const f32x4*)&Olds[row][coff];
            __builtin_nontemporal_store(vv,
                (f32x4*)&dst[((size_t)b * P + h * 64 + row) * C + c0 + coff]);
        }
        __syncthreads();
    }
}

// ---------------------------------------------------------------------------
// Kernel 3: out0 += part (only in split mode).
// ---------------------------------------------------------------------------
__global__ __launch_bounds__(256) void add_partial(
    float* __restrict__ out0, const float* __restrict__ part)
{
    size_t i = ((size_t)blockIdx.x * 256 + threadIdx.x) * 4;
    f32x4 a = *(const f32x4*)&out0[i];
    f32x4 b = *(const f32x4*)&part[i];
    a += b;
    __builtin_nontemporal_store(a, (f32x4*)&out0[i]);
}

extern "C" void kernel_launch(void* const* d_in, const int* in_sizes, int n_in,
                              void* d_out, int out_size, void* d_ws, size_t ws_size,
                              hipStream_t stream) {
    const float* x     = (const float*)d_in[0];
    const float* Wq    = (const float*)d_in[1];
    const float* gamma = (const float*)d_in[2];
    const float* beta  = (const float*)d_in[3];
    const float* mean  = (const float*)d_in[4];
    const float* var   = (const float*)d_in[5];
    const float* gs    = (const float*)d_in[6];

    float* out0 = (float*)d_out;                          // h: (B,P,C)
    float* attn = (float*)d_out + (size_t)B * P * C;      // attn: (B,H,C,C)

    const size_t NE = (size_t)B * C * P;                  // 4M elements
    __bf16* Yhi = (__bf16*)d_ws;                          // 8 MB
    __bf16* Ylo = Yhi + NE;                               // 8 MB
    __bf16* Zhi = Ylo + NE;                               // 8 MB

    // out0-partial for the d-split: 16 MB at d_ws + 24 MB (if it fits)
    const size_t base = 3 * NE * sizeof(__bf16);          // 24 MB
    const bool split = ws_size >= base + NE * sizeof(float);
    float* part = (float*)((char*)d_ws + base);

    // transient scratch in the attn-region tail (dead before attn is written)
    const size_t attn_elems = (size_t)B * H * C * C;
    __bf16* S = (__bf16*)(attn + (attn_elems - 5242880));
    __bf16* xhi = S;
    __bf16* xlo = xhi + (size_t)B * P * C;
    __bf16* whi = xlo + (size_t)B * P * C;
    __bf16* wlo = whi + (size_t)C * C;

    split_hi_lo<<<5120, 256, 0, stream>>>(x, Wq, xhi, xlo, whi, wlo);
    qkv_bn_mfma<<<dim3(16, 8, 8), 256, 0, stream>>>(xhi, xlo, whi, wlo,
                                                    gamma, beta, mean, var,
                                                    Yhi, Ylo, Zhi);
    if (split) {
        attn_fused<<<1024, 256, 0, stream>>>(Yhi, Ylo, Zhi, gs, attn, out0, part, 8);
        add_partial<<<4096, 256, 0, stream>>>(out0, part);
    } else {
        attn_fused<<<512, 256, 0, stream>>>(Yhi, Ylo, Zhi, gs, attn, out0, part, 16);
    }
}

// Round 14
// 333.541 us; speedup vs baseline: 1.3353x; 1.2719x over previous
//
#include <hip/hip_runtime.h>
#include <math.h>

#define B 8
#define P 512
#define C 1024
#define H 8
#define BN_EPS 1e-5f

typedef __attribute__((ext_vector_type(8))) __bf16 bf16x8;
typedef __attribute__((ext_vector_type(4))) __bf16 bf16x4;
typedef __attribute__((ext_vector_type(4))) float f32x4;

// ---------------------------------------------------------------------------
// Kernel 0: split x (B,P,C) and W (C,C) into hi/lo bf16. One float4/thread.
// ---------------------------------------------------------------------------
__global__ __launch_bounds__(256) void split_hi_lo(
    const float* __restrict__ x, const float* __restrict__ Wq,
    __bf16* __restrict__ xhi, __bf16* __restrict__ xlo,
    __bf16* __restrict__ whi, __bf16* __restrict__ wlo)
{
    const size_t NX4 = (size_t)B * P * C / 4;
    size_t idx = (size_t)blockIdx.x * 256 + threadIdx.x;
    float4 v;
    __bf16 *dh, *dl;
    size_t o;
    if (idx < NX4) {
        v = ((const float4*)x)[idx];
        dh = xhi; dl = xlo; o = idx * 4;
    } else {
        v = ((const float4*)Wq)[idx - NX4];
        dh = whi; dl = wlo; o = (idx - NX4) * 4;
    }
    float f[4] = {v.x, v.y, v.z, v.w};
    bf16x4 hv, lv;
    #pragma unroll
    for (int j = 0; j < 4; ++j) {
        __bf16 hb = (__bf16)f[j];
        hv[j] = hb;
        lv[j] = (__bf16)(f[j] - (float)hb);
    }
    *(bf16x4*)&dh[o] = hv;
    *(bf16x4*)&dl[o] = lv;
}

// ---------------------------------------------------------------------------
// Kernel 1: Y[b,d,p] = BN( sum_c W[d,c] * x[b,p,c] ) via split-bf16 MFMA.
// (unchanged — proven)
// ---------------------------------------------------------------------------
__global__ __launch_bounds__(256) void qkv_bn_mfma(
    const __bf16* __restrict__ xhi, const __bf16* __restrict__ xlo,
    const __bf16* __restrict__ whi, const __bf16* __restrict__ wlo,
    const float* __restrict__ gamma, const float* __restrict__ beta,
    const float* __restrict__ mean, const float* __restrict__ var,
    __bf16* __restrict__ Yhi, __bf16* __restrict__ Ylo, __bf16* __restrict__ Zhi)
{
    const int dt = blockIdx.x;   // 16
    const int pt = blockIdx.y;   // 8
    const int b  = blockIdx.z;   // 8
    const int t = threadIdx.x, lane = t & 63, wid = t >> 6;
    const int quadd = (wid >> 1) * 32, quadp = (wid & 1) * 32;
    const int lr = lane & 15, lk = (lane >> 4) * 8;

    const int drow0 = dt * 64 + quadd + lr;
    const size_t xrow0 = ((size_t)b * P + pt * 64 + quadp + lr) * C;

    f32x4 acc[2][2];
    #pragma unroll
    for (int tm = 0; tm < 2; ++tm)
        #pragma unroll
        for (int tn = 0; tn < 2; ++tn)
            acc[tm][tn] = (f32x4){0.f, 0.f, 0.f, 0.f};

    for (int c0 = 0; c0 < C; c0 += 32) {
        const int col = c0 + lk;
        bf16x8 ah[2], al[2], bh[2], bl[2];
        #pragma unroll
        for (int tm = 0; tm < 2; ++tm) {
            size_t ia = (size_t)(drow0 + tm * 16) * C + col;
            ah[tm] = *(const bf16x8*)&whi[ia];
            al[tm] = *(const bf16x8*)&wlo[ia];
        }
        #pragma unroll
        for (int tn = 0; tn < 2; ++tn) {
            size_t ib = xrow0 + (size_t)tn * 16 * C + col;
            bh[tn] = *(const bf16x8*)&xhi[ib];
            bl[tn] = *(const bf16x8*)&xlo[ib];
        }
        #pragma unroll
        for (int tm = 0; tm < 2; ++tm)
            #pragma unroll
            for (int tn = 0; tn < 2; ++tn) {
                acc[tm][tn] = __builtin_amdgcn_mfma_f32_16x16x32_bf16(ah[tm], bh[tn], acc[tm][tn], 0, 0, 0);
                acc[tm][tn] = __builtin_amdgcn_mfma_f32_16x16x32_bf16(ah[tm], bl[tn], acc[tm][tn], 0, 0, 0);
                acc[tm][tn] = __builtin_amdgcn_mfma_f32_16x16x32_bf16(al[tm], bh[tn], acc[tm][tn], 0, 0, 0);
            }
    }

    const int rgrp = (lane >> 4) * 4;
    #pragma unroll
    for (int tm = 0; tm < 2; ++tm) {
        const int dbase = dt * 64 + quadd + tm * 16 + rgrp;
        float4 g4 = *(const float4*)&gamma[dbase];
        float4 bb4 = *(const float4*)&beta[dbase];
        float4 m4 = *(const float4*)&mean[dbase];
        float4 v4 = *(const float4*)&var[dbase];
        float gf[4] = {g4.x, g4.y, g4.z, g4.w};
        float bf[4] = {bb4.x, bb4.y, bb4.z, bb4.w};
        float mf[4] = {m4.x, m4.y, m4.z, m4.w};
        float vf[4] = {v4.x, v4.y, v4.z, v4.w};
        float sc[4];
        #pragma unroll
        for (int r = 0; r < 4; ++r) sc[r] = rsqrtf(vf[r] + BN_EPS) * gf[r];

        #pragma unroll
        for (int tn = 0; tn < 2; ++tn) {
            const int p = pt * 64 + quadp + tn * 16 + lr;
            bf16x4 zq;
            #pragma unroll
            for (int r = 0; r < 4; ++r) {
                float n = (acc[tm][tn][r] - mf[r]) * sc[r] + bf[r];
                __bf16 hb = (__bf16)n;
                __bf16 lb = (__bf16)(n - (float)hb);
                size_t yi = ((size_t)b * C + dbase + r) * P + p;
                Yhi[yi] = hb;
                Ylo[yi] = lb;
                zq[r] = hb;
            }
            *(bf16x4*)&Zhi[((size_t)b * P + p) * C + dbase] = zq;
        }
    }
}

// ---------------------------------------------------------------------------
// Kernel 2 (FUSED v10 = round-6 base, byte-identical structure, + c-side LO
// fragment hoist). Round 6 measured: 210 µs, FETCH 19.5 MB, WRITE 283 MB.
// Only change: al[16] hoisted (c-side lo, loop-invariant) next to the
// already-hoisted ah[16] — cuts phase-1 L2 reads from 3 to 2 loads/step
// (25% of the kernel's L2 read traffic). ~188 VGPR, still 2 waves/SIMD.
// Grid 512: b = id&7 (XCD pin), ct = id>>3 (64 c-tiles of 16). 4 waves.
// ---------------------------------------------------------------------------
__global__ __launch_bounds__(256, 2) void attn_fused(
    const __bf16* __restrict__ Yhi, const __bf16* __restrict__ Ylo,
    const __bf16* __restrict__ Zhi, const float* __restrict__ gs_ptr,
    float* __restrict__ attn, float* __restrict__ out0)
{
    const int id = blockIdx.x;
    const int b  = id & 7;            // XCD pin (dispatch round-robins XCDs)
    const int ct = id >> 3;           // 0..63
    const int c0 = ct * 16;
    const int t = threadIdx.x, lane = t & 63, w = t >> 6;
    const int lr = lane & 15, lk = (lane >> 4) * 8, rgrp = (lane >> 4) * 4;
    const float scale = 1.0f / gs_ptr[0];

    __shared__ __bf16 Plds[8][16][72];   // [h][c16][d64 pad] = 18 KB
    __shared__ float Olds[64][20];       // transpose buffer = 5 KB

    // hoist c-side fragments (hi AND lo): row c0+lr, cols h*64+s*32+lk
    const size_t YbaseC = ((size_t)b * C + c0 + lr) * P;
    bf16x8 ah[16], al[16];
    #pragma unroll
    for (int h = 0; h < H; ++h)
        #pragma unroll
        for (int s = 0; s < 2; ++s) {
            ah[h * 2 + s] = *(const bf16x8*)&Yhi[YbaseC + h * 64 + s * 32 + lk];
            al[h * 2 + s] = *(const bf16x8*)&Ylo[YbaseC + h * 64 + s * 32 + lk];
        }

    f32x4 out_acc[8];
    #pragma unroll
    for (int h = 0; h < H; ++h) out_acc[h] = (f32x4){0.f, 0.f, 0.f, 0.f};

    for (int dbase = 0; dbase < C; dbase += 64) {
        // ---- phase 1: scores 16c x 16d (this wave's d-quarter), all 8 heads
        const int drow = dbase + w * 16 + lr;
        const size_t YbaseD = ((size_t)b * C + drow) * P;

        f32x4 sacc[8];
        #pragma unroll
        for (int h = 0; h < H; ++h) sacc[h] = (f32x4){0.f, 0.f, 0.f, 0.f};

        #pragma unroll
        for (int h = 0; h < H; ++h) {
            #pragma unroll
            for (int s = 0; s < 2; ++s) {
                const int col = h * 64 + s * 32 + lk;
                bf16x8 bh = *(const bf16x8*)&Yhi[YbaseD + col];
                bf16x8 bl = *(const bf16x8*)&Ylo[YbaseD + col];
                sacc[h] = __builtin_amdgcn_mfma_f32_16x16x32_bf16(ah[h * 2 + s], bh, sacc[h], 0, 0, 0);
                sacc[h] = __builtin_amdgcn_mfma_f32_16x16x32_bf16(ah[h * 2 + s], bl, sacc[h], 0, 0, 0);
                sacc[h] = __builtin_amdgcn_mfma_f32_16x16x32_bf16(al[h * 2 + s], bh, sacc[h], 0, 0, 0);
            }
        }

        // ---- softmax over h per (c,d); write attn + P(bf16) to LDS ----
        const int dcol = dbase + w * 16 + lr;
        #pragma unroll
        for (int r = 0; r < 4; ++r) {
            const int c = c0 + rgrp + r;
            float v[8];
            float m = -1e30f;
            #pragma unroll
            for (int h = 0; h < H; ++h) {
                v[h] = sacc[h][r] * scale;
                m = fmaxf(m, v[h]);
            }
            float ssum = 0.f;
            #pragma unroll
            for (int h = 0; h < H; ++h) { v[h] = __expf(v[h] - m); ssum += v[h]; }
            float inv = 1.0f / ssum;
            #pragma unroll
            for (int h = 0; h < H; ++h) {
                float p = v[h] * inv;
                attn[(((size_t)(b * H + h) * C + c) * C) + dcol] = p;
                Plds[h][rgrp + r][w * 16 + lr] = (__bf16)p;
            }
        }

        // ---- issue PV B-side loads before the barrier (overlap) ----
        bf16x8 bv[8][2];
        #pragma unroll
        for (int h = 0; h < H; ++h) {
            const int p = h * 64 + w * 16 + lr;
            #pragma unroll
            for (int kh = 0; kh < 2; ++kh)
                bv[h][kh] = *(const bf16x8*)&Zhi[((size_t)b * P + p) * C + dbase + kh * 32 + lk];
        }
        __syncthreads();

        // ---- phase 2: PV partial (hi-only P, hi-only V) ----
        #pragma unroll
        for (int h = 0; h < H; ++h) {
            #pragma unroll
            for (int kh = 0; kh < 2; ++kh) {
                bf16x8 a = *(const bf16x8*)&Plds[h][lr][kh * 32 + lk];
                out_acc[h] = __builtin_amdgcn_mfma_f32_16x16x32_bf16(a, bv[h][kh], out_acc[h], 0, 0, 0);
            }
        }
        __syncthreads();
    }

    // ---- epilogue: per head, LDS transpose then coalesced out0 store ----
    #pragma unroll
    for (int h = 0; h < H; ++h) {
        #pragma unroll
        for (int r = 0; r < 4; ++r)
            Olds[w * 16 + lr][rgrp + r] = out_acc[h][r];
        __syncthreads();
        {
            const int row = t >> 2;            // 0..63 (p within head)
            const int coff = (t & 3) * 4;      // 0..12
            f32x4 vv = *(const f32x4*)&Olds[row][coff];
            *(f32x4*)&out0[((size_t)b * P + h * 64 + row) * C + c0 + coff] = vv;
        }
        __syncthreads();
    }
}

extern "C" void kernel_launch(void* const* d_in, const int* in_sizes, int n_in,
                              void* d_out, int out_size, void* d_ws, size_t ws_size,
                              hipStream_t stream) {
    const float* x     = (const float*)d_in[0];
    const float* Wq    = (const float*)d_in[1];
    const float* gamma = (const float*)d_in[2];
    const float* beta  = (const float*)d_in[3];
    const float* mean  = (const float*)d_in[4];
    const float* var   = (const float*)d_in[5];
    const float* gs    = (const float*)d_in[6];

    float* out0 = (float*)d_out;                          // h: (B,P,C)
    float* attn = (float*)d_out + (size_t)B * P * C;      // attn: (B,H,C,C)

    const size_t NE = (size_t)B * C * P;                  // 4M elements
    __bf16* Yhi = (__bf16*)d_ws;                          // 8 MB
    __bf16* Ylo = Yhi + NE;                               // 8 MB
    __bf16* Zhi = Ylo + NE;                               // 8 MB

    // transient scratch in the attn-region tail (dead before attn is written)
    const size_t attn_elems = (size_t)B * H * C * C;
    __bf16* S = (__bf16*)(attn + (attn_elems - 5242880));
    __bf16* xhi = S;
    __bf16* xlo = xhi + (size_t)B * P * C;
    __bf16* whi = xlo + (size_t)B * P * C;
    __bf16* wlo = whi + (size_t)C * C;

    split_hi_lo<<<5120, 256, 0, stream>>>(x, Wq, xhi, xlo, whi, wlo);
    qkv_bn_mfma<<<dim3(16, 8, 8), 256, 0, stream>>>(xhi, xlo, whi, wlo,
                                                    gamma, beta, mean, var,
                                                    Yhi, Ylo, Zhi);
    attn_fused<<<512, 256, 0, stream>>>(Yhi, Ylo, Zhi, gs, attn, out0);
}